// Round 7
// baseline (109.481 us; speedup 1.0000x reference)
//
#include <hip/hip_runtime.h>

// FeatureEmbedder: out[b, f*64+d] = relu(x[b,f] * W[f,d] + b[f,d])
// x: [16384, 128] f32, W: [128, 64] f32, b: [128, 64] f32
// out: [16384, 8192] f32  (512 MB -> HBM-write-bound)
//
// R7: fill-mimic sweeping window. R5/R6 gave each block a private 1 MB
// region -> instantaneous GPU write footprint = 512 scattered 4 KB chunks,
// i.e. ~512 page streams per DRAM channel (>> ~32 banks) -> row-buffer
// thrash at 5.1 TB/s. rocclr's fill (6.8 TB/s @ 10.6% occupancy) is a
// grid-stride sweep: all waves write inside ONE contiguous ~1 MB window
// that advances -> few open pages per bank, all row hits. Mimic exactly:
// 256 blocks x 256 threads, iter i writes out4[i*65536 + gtid]. 65536 is a
// multiple of 2048 (row width in float4), so each thread's column and W/b
// fragment stay loop-invariant. x: 16 B/wave/iter, double-buffered in
// registers (16-deep groups, static indices) so loads pipeline ahead of
// compute and never serialize against the store stream.

#define BATCH 16384
#define NFEAT 128
#define EMBD  64
#define ROW4  (NFEAT * EMBD / 4)   // 2048 float4 per output row
#define GRID4 65536                // float4 per sweep step (1 MB window)
#define XSTEP (32 * NFEAT)         // x floats per sweep step (32 rows)

typedef float vfloat4 __attribute__((ext_vector_type(4)));

__global__ __launch_bounds__(256) void feature_embed_kernel(
    const float* __restrict__ x,
    const vfloat4* __restrict__ W4,
    const vfloat4* __restrict__ B4,
    vfloat4* __restrict__ out4) {

    const int tid  = threadIdx.x;         // 0..255
    const int bid  = blockIdx.x;          // 0..255
    const int gtid = bid * 256 + tid;     // 0..65535
    const int col4 = gtid & (ROW4 - 1);   // loop-invariant column
    const int f    = col4 >> 4;           // loop-invariant feature
    const int rb   = bid >> 3;            // row offset within each step, 0..31

    const vfloat4 w  = W4[col4];
    const vfloat4 bb = B4[col4];

    const float* xp = x + rb * NFEAT + f; // + iter*XSTEP
    vfloat4* op     = out4 + gtid;        // + iter*GRID4

    float xa[16], xb[16];

    // Prologue: load group 0.
    #pragma unroll
    for (int k = 0; k < 16; ++k) xa[k] = xp[k * XSTEP];

    for (int g0 = 0; g0 < 512; g0 += 32) {
        // Load group g0+16 while computing/storing group g0.
        #pragma unroll
        for (int k = 0; k < 16; ++k) xb[k] = xp[(g0 + 16 + k) * XSTEP];
        #pragma unroll
        for (int k = 0; k < 16; ++k) {
            vfloat4 o;
            o.x = fmaxf(fmaf(xa[k], w.x, bb.x), 0.0f);
            o.y = fmaxf(fmaf(xa[k], w.y, bb.y), 0.0f);
            o.z = fmaxf(fmaf(xa[k], w.z, bb.z), 0.0f);
            o.w = fmaxf(fmaf(xa[k], w.w, bb.w), 0.0f);
            op[(g0 + k) * GRID4] = o;     // GPU-wide 1 MB sweeping window
        }
        // Load group g0+32 while computing/storing group g0+16.
        if (g0 + 32 < 512) {
            #pragma unroll
            for (int k = 0; k < 16; ++k) xa[k] = xp[(g0 + 32 + k) * XSTEP];
        }
        #pragma unroll
        for (int k = 0; k < 16; ++k) {
            vfloat4 o;
            o.x = fmaxf(fmaf(xb[k], w.x, bb.x), 0.0f);
            o.y = fmaxf(fmaf(xb[k], w.y, bb.y), 0.0f);
            o.z = fmaxf(fmaf(xb[k], w.z, bb.z), 0.0f);
            o.w = fmaxf(fmaf(xb[k], w.w, bb.w), 0.0f);
            op[(g0 + 16 + k) * GRID4] = o;
        }
    }
}

extern "C" void kernel_launch(void* const* d_in, const int* in_sizes, int n_in,
                              void* d_out, int out_size, void* d_ws, size_t ws_size,
                              hipStream_t stream) {
    const float*   x  = (const float*)d_in[0];
    const vfloat4* W4 = (const vfloat4*)d_in[1];
    const vfloat4* B4 = (const vfloat4*)d_in[2];
    vfloat4* out4     = (vfloat4*)d_out;

    // 256 blocks x 256 threads: one workgroup per CU, grid-stride sweep.
    feature_embed_kernel<<<256, 256, 0, stream>>>(x, W4, B4, out4);
}

// Round 8
// 102.209 us; speedup vs baseline: 1.0711x; 1.0711x over previous
//
#include <hip/hip_runtime.h>

// FeatureEmbedder: out[b, f*64+d] = relu(x[b,f] * W[f,d] + b[f,d])
// x: [16384, 128] f32, W: [128, 64] f32, b: [128, 64] f32
// out: [16384, 8192] f32  (512 MB -> HBM-write-bound)
//
// R8: halve the concurrent-stream count. Perf so far tracks DRAM page
// locality of the AGGREGATE write stream: 2048 page-jumping streams 4.4 TB/s
// (R0) < ~256 drifting windows w/ 1MB per-wave strides 4.7 (R7) < 512 linear
// streams 5.1 (R5/R6) < 1 linear stream 6.8 (fill). Each HBM pseudo-channel
// has ~32-64 banks; 512 interleaved streams per channel thrash row buffers.
// This round: 256 blocks x 512 threads, block b sweeps a private CONTIGUOUS
// 2 MB region (rows 64b..64b+63) linearly in 8 KB chunks -> 256 streams.
// Same proven per-block structure as R5: x-tile staged in LDS (32 KB),
// 4 hoisted W/b pairs per thread, conflict-free broadcast ds_reads,
// pure-store vmcnt stream.

#define BATCH 16384
#define NFEAT 128
#define EMBD  64
#define ROW4  (NFEAT * EMBD / 4)   // 2048 float4 per output row

typedef float vfloat4 __attribute__((ext_vector_type(4)));

__global__ __launch_bounds__(512) void feature_embed_kernel(
    const vfloat4* __restrict__ x4,
    const vfloat4* __restrict__ W4,
    const vfloat4* __restrict__ B4,
    vfloat4* __restrict__ out4) {

    __shared__ float xs[64 * NFEAT];      // 32 KB: x rows 64b .. 64b+63

    const int tid = threadIdx.x;          // 0..511
    const int b   = blockIdx.x;           // 0..255

    // Thread's column for sub-chunk j: col4 = j*512 + tid, j = 0..3.
    vfloat4 wv[4], bv[4];
    #pragma unroll
    for (int j = 0; j < 4; ++j) {
        wv[j] = W4[j * 512 + tid];
        bv[j] = B4[j * 512 + tid];
    }

    // Stage x rows 64b..64b+63 (8192 floats = 2048 float4, contiguous in x).
    #pragma unroll
    for (int k = 0; k < 4; ++k)
        ((vfloat4*)xs)[k * 512 + tid] = x4[b * 2048 + k * 512 + tid];
    __syncthreads();

    const int fs = tid >> 4;              // 0..31: feature sub-index
    vfloat4* outb = out4 + b * 64 * ROW4; // this block's 2 MB region

    #pragma unroll 2
    for (int r = 0; r < 64; ++r) {
        const float* xr = xs + r * NFEAT;
        vfloat4* outr = outb + r * ROW4;
        #pragma unroll
        for (int j = 0; j < 4; ++j) {
            const float xv = xr[j * 32 + fs];     // ds_read broadcast (4 banks)
            vfloat4 o;
            o.x = fmaxf(fmaf(xv, wv[j].x, bv[j].x), 0.0f);
            o.y = fmaxf(fmaf(xv, wv[j].y, bv[j].y), 0.0f);
            o.z = fmaxf(fmaf(xv, wv[j].z, bv[j].z), 0.0f);
            o.w = fmaxf(fmaf(xv, wv[j].w, bv[j].w), 0.0f);
            // Block sweep: chunk (r*4+j) is the next 8 KB of the 2 MB region.
            outr[j * 512 + tid] = o;
        }
    }
}

extern "C" void kernel_launch(void* const* d_in, const int* in_sizes, int n_in,
                              void* d_out, int out_size, void* d_ws, size_t ws_size,
                              hipStream_t stream) {
    const vfloat4* x4 = (const vfloat4*)d_in[0];
    const vfloat4* W4 = (const vfloat4*)d_in[1];
    const vfloat4* B4 = (const vfloat4*)d_in[2];
    vfloat4* out4     = (vfloat4*)d_out;

    // 256 blocks x 512 threads: 1 block/CU, block b writes rows [64b, 64b+64).
    feature_embed_kernel<<<256, 512, 0, stream>>>(x4, W4, B4, out4);
}